// Round 7
// baseline (61.380 us; speedup 1.0000x reference)
//
#include <hip/hip_runtime.h>

static constexpr int HD   = 128;   // head dim
static constexpr int HH   = 64;    // height
static constexpr int WW   = 64;    // width
static constexpr int ROWS = 2;     // tile rows per block
static constexpr int BLK  = 512;   // 4 threads per pixel (d-quarters)
static constexpr int HALO = ROWS + 2;     // 4 halo rows
static constexpr int DC   = 16;    // d-planes per chunk
static constexpr int NCH  = HD / DC;      // 8 chunks
static constexpr int LSTR = 16;    // dense per-pixel stride; XOR swizzle kills conflicts
static constexpr float SCALE = 0.08838834764831845f;  // 128^-0.5

// Thread (px, qf) owns planes d = c*16 + 4*qf + p (p<4) of pixel px.
// LDS column swizzle: group g of column ws lives at quad (g ^ ((ws>>2)&3)).
// Write banks 4(ws&1)+(g^((ws>>2)&3)) and read banks 4(cc&1)+(qf^((cc>>2)&3))
// are both uniform over every 16-lane subgroup -> minimal-cycle b128 ops.
__global__ __launch_bounds__(BLK, 8) void natten3_kernel(
    const float* __restrict__ Q, const float* __restrict__ K,
    const float* __restrict__ V, float* __restrict__ O)
{
  __shared__ float buf[2][HALO * WW * LSTR];   // 2 x 16 KB; 4 blocks = 128 KiB

  const int tid = threadIdx.x;
  const int qf  = tid & 3;               // d-quarter
  const int px  = tid >> 2;              // 0..127 pixel in tile
  const int w   = px & 63;
  const int pr  = px >> 6;               // tile row 0/1

  // XCD-chunked swizzle: 1024 blocks, 128 consecutive tiles per XCD
  const int bid = blockIdx.x;
  const int swz = (bid & 7) * 128 + (bid >> 3);
  const int b   = swz >> 5;              // image
  const int h0  = (swz & 31) * ROWS;     // tile top row
  const int hh  = h0 + pr;

  const int plane = HH * WW;             // 4096
  const size_t img = (size_t)HD * plane;
  const float* Qb = Q + (size_t)b * img;
  const float* Kb = K + (size_t)b * img;
  const float* Vb = V + (size_t)b * img;
  const int qoff = hh * WW + w;
  const int dq   = 4 * qf;

  // staging map: 1024 float4-groups = 4 halo rows x 64 w x 4 pgroups, 2/thread
  int sg_g[2], sg_l[2];
  #pragma unroll
  for (int it = 0; it < 2; ++it) {
    const int idx  = it * BLK + tid;     // 0..1023
    const int ws   = idx & 63;
    const int rest = idx >> 6;           // 0..15
    const int is   = rest >> 2;          // halo row 0..3
    const int gs   = rest & 3;           // plane group 0..3
    const int grow = min(max(h0 - 1 + is, 0), HH - 1);
    sg_g[it] = gs * 4 * plane + grow * WW + ws;
    sg_l[it] = (is * WW + ws) * LSTR + 4 * (gs ^ ((ws >> 2) & 3));
  }

  // neighbor LDS offsets (my quarter, swizzled)
  int lofs[9];
  #pragma unroll
  for (int dh = 0; dh < 3; ++dh) {
    #pragma unroll
    for (int dw = 0; dw < 3; ++dw) {
      const int j  = dh * 3 + dw;
      const int cc = min(max(w + dw - 1, 0), WW - 1);
      lofs[j] = ((pr + dh) * WW + cc) * LSTR + 4 * (qf ^ ((cc >> 2) & 3));
    }
  }

  // ================= Phase 1: logits =================
  {  // chunk 0: direct stage
    float s0[2][4];
    #pragma unroll
    for (int it = 0; it < 2; ++it)
      #pragma unroll
      for (int p = 0; p < 4; ++p)
        s0[it][p] = Kb[sg_g[it] + p * plane];
    #pragma unroll
    for (int it = 0; it < 2; ++it)
      *(float4*)&buf[0][sg_l[it]] = make_float4(s0[it][0], s0[it][1], s0[it][2], s0[it][3]);
  }
  float s[2][2][4];                      // 2-deep staging registers
  #pragma unroll
  for (int it = 0; it < 2; ++it)         // issue chunk 1 now
    #pragma unroll
    for (int p = 0; p < 4; ++p)
      s[1][it][p] = Kb[DC * plane + sg_g[it] + p * plane];
  float q[3][4];                         // 3-slot Q rotation
  #pragma unroll
  for (int p = 0; p < 4; ++p) q[0][p] = Qb[(dq + p) * plane + qoff];
  #pragma unroll
  for (int p = 0; p < 4; ++p) q[1][p] = Qb[(DC + dq + p) * plane + qoff];
  __syncthreads();

  float logit[9];
  #pragma unroll
  for (int j = 0; j < 9; ++j) logit[j] = 0.0f;

  #pragma unroll
  for (int c = 0; c < NCH; ++c) {
    const int cur = c & 1;
    if (c + 2 < NCH) {                   // issue chunk c+2 into the freed set
      const int dbase = (c + 2) * DC * plane;
      #pragma unroll
      for (int it = 0; it < 2; ++it)
        #pragma unroll
        for (int p = 0; p < 4; ++p)
          s[cur][it][p] = Kb[dbase + sg_g[it] + p * plane];
      #pragma unroll
      for (int p = 0; p < 4; ++p)
        q[(c + 2) % 3][p] = Qb[((c + 2) * DC + dq + p) * plane + qoff];
    }
    const float* __restrict__ bc = buf[cur];
    const float* __restrict__ qc = q[c % 3];
    #pragma unroll
    for (int j = 0; j < 9; ++j) {
      const float4 k4 = *(const float4*)&bc[lofs[j]];
      float acc = logit[j];
      acc = fmaf(qc[0], k4.x, acc); acc = fmaf(qc[1], k4.y, acc);
      acc = fmaf(qc[2], k4.z, acc); acc = fmaf(qc[3], k4.w, acc);
      logit[j] = acc;
    }
    if (c + 1 < NCH) {                   // write chunk c+1 (loaded last iter)
      #pragma unroll
      for (int it = 0; it < 2; ++it)
        *(float4*)&buf[cur ^ 1][sg_l[it]] =
            make_float4(s[(c + 1) & 1][it][0], s[(c + 1) & 1][it][1],
                        s[(c + 1) & 1][it][2], s[(c + 1) & 1][it][3]);
    }
    __syncthreads();
  }

  // issue V chunks 0 and 1 now; reduction+softmax hides their latency
  float v[2][2][4];
  #pragma unroll
  for (int it = 0; it < 2; ++it)
    #pragma unroll
    for (int p = 0; p < 4; ++p)
      v[0][it][p] = Vb[sg_g[it] + p * plane];
  #pragma unroll
  for (int it = 0; it < 2; ++it)
    #pragma unroll
    for (int p = 0; p < 4; ++p)
      v[1][it][p] = Vb[DC * plane + sg_g[it] + p * plane];

  // quad-reduce partial logits (lanes 4m..4m+3 share a pixel)
  #pragma unroll
  for (int j = 0; j < 9; ++j) {
    logit[j] += __shfl_xor(logit[j], 1);
    logit[j] += __shfl_xor(logit[j], 2);
  }
  // masks computed here (kept out of the phase-1 live set)
  float att[9];
  float Z = 0.0f;
  {
    float msk[9];
    #pragma unroll
    for (int dh = 0; dh < 3; ++dh)
      #pragma unroll
      for (int dw = 0; dw < 3; ++dw) {
        const int j = dh * 3 + dw;
        const int r = hh + dh - 1, c = w + dw - 1;
        msk[j] = (r >= 0 && r < HH && c >= 0 && c < WW) ? 1.0f : 0.0f;
      }
    #pragma unroll
    for (int j = 0; j < 9; ++j) logit[j] = msk[j] * logit[j] * SCALE;
    float m = logit[0];
    #pragma unroll
    for (int j = 1; j < 9; ++j) m = fmaxf(m, logit[j]);
    #pragma unroll
    for (int j = 0; j < 9; ++j) { att[j] = __expf(logit[j] - m); Z += att[j]; }
    const float rZ = 1.0f / Z;
    #pragma unroll
    for (int j = 0; j < 9; ++j) att[j] *= rZ * msk[j];
  }

  // ================= Phase 2: PV =================
  // buf[0] reads sealed by phase-1 iter-6 barrier; write V chunk 0
  #pragma unroll
  for (int it = 0; it < 2; ++it)
    *(float4*)&buf[0][sg_l[it]] = make_float4(v[0][it][0], v[0][it][1], v[0][it][2], v[0][it][3]);
  __syncthreads();

  const size_t obase = ((size_t)b * plane + (size_t)h0 * WW) * HD;
  float oprev[4];
  #pragma unroll
  for (int c = 0; c < NCH; ++c) {
    const int cur = c & 1;
    if (c + 2 < NCH) {                   // issue V chunk c+2
      const int dbase = (c + 2) * DC * plane;
      #pragma unroll
      for (int it = 0; it < 2; ++it)
        #pragma unroll
        for (int p = 0; p < 4; ++p)
          v[cur][it][p] = Vb[dbase + sg_g[it] + p * plane];
    }
    float o0 = 0.f, o1 = 0.f, o2 = 0.f, o3 = 0.f;
    const float* __restrict__ bc = buf[cur];
    #pragma unroll
    for (int j = 0; j < 9; ++j) {
      const float4 v4 = *(const float4*)&bc[lofs[j]];
      const float a = att[j];
      o0 = fmaf(a, v4.x, o0); o1 = fmaf(a, v4.y, o1);
      o2 = fmaf(a, v4.z, o2); o3 = fmaf(a, v4.w, o3);
    }
    if (c & 1) {
      // paired writeout: quad covers one full 128B sector of its pixel
      const size_t oa = obase + (size_t)px * HD + (size_t)(c - 1) * DC + dq;
      *(float4*)&O[oa]      = make_float4(oprev[0], oprev[1], oprev[2], oprev[3]);
      *(float4*)&O[oa + DC] = make_float4(o0, o1, o2, o3);
    } else {
      oprev[0] = o0; oprev[1] = o1; oprev[2] = o2; oprev[3] = o3;
    }
    if (c + 1 < NCH) {                   // write V chunk c+1 (loaded last iter)
      #pragma unroll
      for (int it = 0; it < 2; ++it)
        *(float4*)&buf[cur ^ 1][sg_l[it]] =
            make_float4(v[(c + 1) & 1][it][0], v[(c + 1) & 1][it][1],
                        v[(c + 1) & 1][it][2], v[(c + 1) & 1][it][3]);
      __syncthreads();
    }
  }
}

extern "C" void kernel_launch(void* const* d_in, const int* in_sizes, int n_in,
                              void* d_out, int out_size, void* d_ws, size_t ws_size,
                              hipStream_t stream) {
  const float* q = (const float*)d_in[0];
  const float* k = (const float*)d_in[1];
  const float* v = (const float*)d_in[2];
  float* o = (float*)d_out;
  const int nblocks = 32 * (HH / ROWS);   // 1024
  natten3_kernel<<<dim3(nblocks), dim3(BLK), 0, stream>>>(q, k, v, o);
}

// Round 8
// 42.875 us; speedup vs baseline: 1.4316x; 1.4316x over previous
//
#include <hip/hip_runtime.h>

static constexpr int HD   = 128;   // head dim
static constexpr int HH   = 64;    // height
static constexpr int WW   = 64;    // width
static constexpr int ROWS = 2;     // tile rows per block
static constexpr int BLK  = 512;   // 4 threads per pixel (d-quarters)
static constexpr int HALO = ROWS + 2;     // 4 halo rows
static constexpr int DC   = 16;    // d-planes per chunk
static constexpr int NCH  = HD / DC;      // 8 chunks
static constexpr int LSTR = 16;    // dense stride + XOR quad swizzle (R7-validated)
static constexpr float SCALE = 0.08838834764831845f;  // 128^-0.5

// Thread (px, qf) owns planes d = c*16 + 4*qf + p (p<4) of pixel px.
// LDS swizzle: plane-group g of column ws lives at quad (g ^ ((ws>>2)&3)).
// Same bijection on write (gs) and read (qf) sides -> conflict-minimal b128.
// Structure is exactly round-6's (proven 46.6us): 1-deep prefetch, runtime loop.
__global__ __launch_bounds__(BLK, 4) void natten3_kernel(
    const float* __restrict__ Q, const float* __restrict__ K,
    const float* __restrict__ V, float* __restrict__ O)
{
  __shared__ float buf[2][HALO * WW * LSTR];   // 2 x 16 KB

  const int tid = threadIdx.x;
  const int qf  = tid & 3;               // d-quarter
  const int px  = tid >> 2;              // 0..127 pixel in tile
  const int w   = px & 63;
  const int pr  = px >> 6;               // tile row 0/1

  // XCD-chunked swizzle: 1024 blocks, 128 consecutive tiles per XCD
  const int bid = blockIdx.x;
  const int swz = (bid & 7) * 128 + (bid >> 3);
  const int b   = swz >> 5;              // image
  const int h0  = (swz & 31) * ROWS;     // tile top row
  const int hh  = h0 + pr;

  const int plane = HH * WW;             // 4096
  const size_t img = (size_t)HD * plane;
  const float* Qb = Q + (size_t)b * img;
  const float* Kb = K + (size_t)b * img;
  const float* Vb = V + (size_t)b * img;
  const int qoff = hh * WW + w;
  const int dq   = 4 * qf;

  // staging map: 1024 float4-groups = 4 halo rows x 64 w x 4 pgroups, 2/thread
  int sg_g[2], sg_l[2];
  #pragma unroll
  for (int it = 0; it < 2; ++it) {
    const int idx  = it * BLK + tid;     // 0..1023
    const int ws   = idx & 63;
    const int rest = idx >> 6;           // 0..15
    const int is   = rest >> 2;          // halo row 0..3
    const int gs   = rest & 3;           // plane group 0..3
    const int grow = min(max(h0 - 1 + is, 0), HH - 1);
    sg_g[it] = gs * 4 * plane + grow * WW + ws;
    sg_l[it] = (is * WW + ws) * LSTR + 4 * (gs ^ ((ws >> 2) & 3));
  }

  // neighbor LDS offsets (my quarter, swizzled) + validity masks
  int   lofs[9];
  float msk[9];
  #pragma unroll
  for (int dh = 0; dh < 3; ++dh) {
    #pragma unroll
    for (int dw = 0; dw < 3; ++dw) {
      const int j = dh * 3 + dw;
      const int r = hh + dh - 1, c = w + dw - 1;
      msk[j] = (r >= 0 && r < HH && c >= 0 && c < WW) ? 1.0f : 0.0f;
      const int cc = min(max(c, 0), WW - 1);
      lofs[j] = ((pr + dh) * WW + cc) * LSTR + 4 * (qf ^ ((cc >> 2) & 3));
    }
  }

  // ================= Phase 1: logits =================
  {
    float s[2][4];
    #pragma unroll
    for (int it = 0; it < 2; ++it)
      #pragma unroll
      for (int p = 0; p < 4; ++p)
        s[it][p] = Kb[sg_g[it] + p * plane];
    #pragma unroll
    for (int it = 0; it < 2; ++it)
      *(float4*)&buf[0][sg_l[it]] = make_float4(s[it][0], s[it][1], s[it][2], s[it][3]);
  }
  float q[4];
  #pragma unroll
  for (int p = 0; p < 4; ++p) q[p] = Qb[(dq + p) * plane + qoff];
  __syncthreads();

  float logit[9];
  #pragma unroll
  for (int j = 0; j < 9; ++j) logit[j] = 0.0f;

  for (int c = 0; c < NCH; ++c) {
    const int cur = c & 1;
    float s[2][4], qn[4];
    if (c + 1 < NCH) {                   // issue next chunk's loads early
      const int dbase = (c + 1) * DC * plane;
      #pragma unroll
      for (int it = 0; it < 2; ++it)
        #pragma unroll
        for (int p = 0; p < 4; ++p)
          s[it][p] = Kb[dbase + sg_g[it] + p * plane];
      #pragma unroll
      for (int p = 0; p < 4; ++p)
        qn[p] = Qb[((c + 1) * DC + dq + p) * plane + qoff];
    }
    const float* __restrict__ bc = buf[cur];
    #pragma unroll
    for (int j = 0; j < 9; ++j) {
      const float4 k4 = *(const float4*)&bc[lofs[j]];
      float acc = logit[j];
      acc = fmaf(q[0], k4.x, acc); acc = fmaf(q[1], k4.y, acc);
      acc = fmaf(q[2], k4.z, acc); acc = fmaf(q[3], k4.w, acc);
      logit[j] = acc;
    }
    if (c + 1 < NCH) {
      #pragma unroll
      for (int it = 0; it < 2; ++it)
        *(float4*)&buf[cur ^ 1][sg_l[it]] = make_float4(s[it][0], s[it][1], s[it][2], s[it][3]);
      #pragma unroll
      for (int p = 0; p < 4; ++p) q[p] = qn[p];
    }
    __syncthreads();
  }

  // issue V chunk-0 staging loads now; softmax math hides their latency
  float vs[2][4];
  #pragma unroll
  for (int it = 0; it < 2; ++it)
    #pragma unroll
    for (int p = 0; p < 4; ++p)
      vs[it][p] = Vb[sg_g[it] + p * plane];

  // quad-reduce partial logits (lanes 4m..4m+3 share a pixel)
  #pragma unroll
  for (int j = 0; j < 9; ++j) {
    logit[j] += __shfl_xor(logit[j], 1);
    logit[j] += __shfl_xor(logit[j], 2);
  }
  // softmax over 9 (OOB logits = 0 participate in denominator)
  #pragma unroll
  for (int j = 0; j < 9; ++j) logit[j] = msk[j] * logit[j] * SCALE;
  float m = logit[0];
  #pragma unroll
  for (int j = 1; j < 9; ++j) m = fmaxf(m, logit[j]);
  float att[9];
  float Z = 0.0f;
  #pragma unroll
  for (int j = 0; j < 9; ++j) { att[j] = __expf(logit[j] - m); Z += att[j]; }
  const float rZ = 1.0f / Z;
  #pragma unroll
  for (int j = 0; j < 9; ++j) att[j] *= rZ * msk[j];

  // ================= Phase 2: PV =================
  // buf[0] reads finished at phase-1's final barrier; stage V chunk 0
  #pragma unroll
  for (int it = 0; it < 2; ++it)
    *(float4*)&buf[0][sg_l[it]] = make_float4(vs[it][0], vs[it][1], vs[it][2], vs[it][3]);
  __syncthreads();

  const size_t obase = ((size_t)b * plane + (size_t)h0 * WW) * HD;
  float oprev[4];
  for (int c = 0; c < NCH; ++c) {
    const int cur = c & 1;
    float s[2][4];
    if (c + 1 < NCH) {
      const int dbase = (c + 1) * DC * plane;
      #pragma unroll
      for (int it = 0; it < 2; ++it)
        #pragma unroll
        for (int p = 0; p < 4; ++p)
          s[it][p] = Vb[dbase + sg_g[it] + p * plane];
    }
    float o0 = 0.f, o1 = 0.f, o2 = 0.f, o3 = 0.f;
    const float* __restrict__ bc = buf[cur];
    #pragma unroll
    for (int j = 0; j < 9; ++j) {
      const float4 v4 = *(const float4*)&bc[lofs[j]];
      const float a = att[j];
      o0 = fmaf(a, v4.x, o0); o1 = fmaf(a, v4.y, o1);
      o2 = fmaf(a, v4.z, o2); o3 = fmaf(a, v4.w, o3);
    }
    if (c & 1) {
      // paired writeout: quad covers one full 128B sector of its pixel
      const size_t oa = obase + (size_t)px * HD + (size_t)(c - 1) * DC + dq;
      *(float4*)&O[oa]      = make_float4(oprev[0], oprev[1], oprev[2], oprev[3]);
      *(float4*)&O[oa + DC] = make_float4(o0, o1, o2, o3);
    } else {
      oprev[0] = o0; oprev[1] = o1; oprev[2] = o2; oprev[3] = o3;
    }
    if (c + 1 < NCH) {
      #pragma unroll
      for (int it = 0; it < 2; ++it)
        *(float4*)&buf[cur ^ 1][sg_l[it]] = make_float4(s[it][0], s[it][1], s[it][2], s[it][3]);
      __syncthreads();
    }
  }
}

extern "C" void kernel_launch(void* const* d_in, const int* in_sizes, int n_in,
                              void* d_out, int out_size, void* d_ws, size_t ws_size,
                              hipStream_t stream) {
  const float* q = (const float*)d_in[0];
  const float* k = (const float*)d_in[1];
  const float* v = (const float*)d_in[2];
  float* o = (float*)d_out;
  const int nblocks = 32 * (HH / ROWS);   // 1024
  natten3_kernel<<<dim3(nblocks), dim3(BLK), 0, stream>>>(q, k, v, o);
}